// Round 10
// baseline (350.965 us; speedup 1.0000x reference)
//
#include <hip/hip_runtime.h>

typedef unsigned short u16;
typedef __attribute__((ext_vector_type(8))) short short8;
typedef __attribute__((ext_vector_type(4))) float f32x4;

#define MFMA(a, b, c) __builtin_amdgcn_mfma_f32_16x16x32_bf16((a), (b), (c), 0, 0, 0)

__device__ inline float bf2f(u16 u) {
  union { unsigned int i; float f; } w; w.i = ((unsigned int)u) << 16; return w.f;
}
__device__ inline u16 f2bf(float x) {
  union { float f; unsigned int i; } u; u.f = x;
  unsigned int r = u.i + 0x7fffu + ((u.i >> 16) & 1u);  // RNE
  return (u16)(r >> 16);
}
__device__ inline unsigned int pk2(float a, float b) {
  return (unsigned int)f2bf(a) | ((unsigned int)f2bf(b) << 16);
}
__device__ inline void unpack8(uint4 v, float* f) {
  union { unsigned int i; float g; } c;
  c.i = v.x << 16;          f[0] = c.g;
  c.i = v.x & 0xffff0000u;  f[1] = c.g;
  c.i = v.y << 16;          f[2] = c.g;
  c.i = v.y & 0xffff0000u;  f[3] = c.g;
  c.i = v.z << 16;          f[4] = c.g;
  c.i = v.z & 0xffff0000u;  f[5] = c.g;
  c.i = v.w << 16;          f[6] = c.g;
  c.i = v.w & 0xffff0000u;  f[7] = c.g;
}

// ---------------- workspace layout (bytes) ----------------
static const size_t SZ_QKV = (size_t)48 * 1024 * 64 * 2;     // 6,291,456
static const size_t SZ_MAP = (size_t)48 * 1024 * 1024 * 2;   // 100,663,296
static const size_t OFF_Q  = 0;
static const size_t OFF_K  = OFF_Q + SZ_QKV;
static const size_t OFF_VT = OFF_K + SZ_QKV;
static const size_t OFF_S  = OFF_VT + SZ_QKV;                // S bf16; DEAD after conv -> U aliases
static const size_t OFF_UG = OFF_S;                          // U f32 [48][1024][64] (aliases S)
static const size_t OFF_QM = OFF_S + SZ_MAP;                 // Q = N*P-1 bf16 [48 bh][1024][1024]
static const size_t OFF_OT = OFF_QM + SZ_MAP;                // o_tmp [B,N,C] bf16
static const size_t OFF_ST = OFF_OT + SZ_QKV;                // stats 48*2 f32
static const size_t OFF_CS = OFF_ST + 896;                   // colsum_v 48*64 f32

// ---------------- K1: qkv = x @ w_qkv^T, scatter to q,k,vT + fused colsum ----------------
__global__ __launch_bounds__(256, 3) void k_qkv(const float* __restrict__ x,
                                                const float* __restrict__ w,
                                                u16* __restrict__ qb,
                                                u16* __restrict__ kb,
                                                u16* __restrict__ vT,
                                                float* __restrict__ colsum) {
  __shared__ u16 SH[16384];          // As | Bs ; reused as epilogue staging
  u16* As = SH;
  u16* Bs = SH + 8192;
  const int t = threadIdx.x;
  const int m0 = blockIdx.x * 128;
  const int n0 = blockIdx.y * 128;
  const int wave = t >> 6, lane = t & 63;
  const int wm = (wave & 1) * 64, wn = (wave >> 1) * 64;
  const int fr = lane & 15;
  const int fk = (lane >> 4) * 8;
  f32x4 acc[4][4] = {};
  for (int k0 = 0; k0 < 384; k0 += 64) {
#pragma unroll
    for (int i = 0; i < 4; ++i) {
      int e = (i * 256 + t) * 8;
      int row = e >> 6, col = e & 63;
      const float* xp = &x[(size_t)(m0 + row) * 384 + k0 + col];
      const float* wp = &w[(size_t)(n0 + row) * 384 + k0 + col];
      float4 a0 = *(const float4*)xp, a1 = *(const float4*)(xp + 4);
      uint4 av; av.x = pk2(a0.x, a0.y); av.y = pk2(a0.z, a0.w);
      av.z = pk2(a1.x, a1.y); av.w = pk2(a1.z, a1.w);
      *(uint4*)&As[e] = av;
      float4 b0 = *(const float4*)wp, b1 = *(const float4*)(wp + 4);
      uint4 bv; bv.x = pk2(b0.x, b0.y); bv.y = pk2(b0.z, b0.w);
      bv.z = pk2(b1.x, b1.y); bv.w = pk2(b1.z, b1.w);
      *(uint4*)&Bs[e] = bv;
    }
    __syncthreads();
#pragma unroll
    for (int ks = 0; ks < 2; ++ks) {
      const int ko = ks * 32 + fk;
      short8 a[4], b[4];
#pragma unroll
      for (int mi = 0; mi < 4; ++mi) a[mi] = *(const short8*)&As[(wm + mi * 16 + fr) * 64 + ko];
#pragma unroll
      for (int ni = 0; ni < 4; ++ni) b[ni] = *(const short8*)&Bs[(wn + ni * 16 + fr) * 64 + ko];
#pragma unroll
      for (int mi = 0; mi < 4; ++mi)
#pragma unroll
        for (int ni = 0; ni < 4; ++ni) acc[mi][ni] = MFMA(a[mi], b[ni], acc[mi][ni]);
    }
    __syncthreads();
  }
  // ---- epilogue: per-wave LDS transpose, then full-line uint4 stores
  u16* st = &SH[wave * 4096];
  const int gcb = n0 + wn;                 // 64-aligned -> single (s,h) per wave
  const int s = gcb / 384;
  const int remb = gcb - s * 384;
  const int h = remb >> 6;
#pragma unroll
  for (int mi = 0; mi < 4; ++mi)
#pragma unroll
    for (int ni = 0; ni < 4; ++ni)
#pragma unroll
      for (int r = 0; r < 4; ++r) {
        int rl = mi * 16 + (lane >> 4) * 4 + r;   // n-local 0..63
        int cl = ni * 16 + fr;                    // d-local 0..63
        u16 val = f2bf(acc[mi][ni][r]);
        if (s == 2) st[cl * 64 + rl] = val;       // transpose for vT
        else        st[rl * 64 + cl] = val;
      }
  const int gm0 = m0 + wm;                 // 64-aligned
  const int b_ = gm0 >> 10;
  const size_t base = (size_t)(b_ * 6 + h) << 16;
  const int nloc = gm0 & 1023;
  const int r8 = lane >> 3, c8 = (lane & 7) * 8;
#pragma unroll
  for (int i = 0; i < 8; ++i) {
    int lrow = i * 8 + r8;
    uint4 v = *(const uint4*)&st[lrow * 64 + c8];
    if (s == 0)      *(uint4*)&qb[base + (size_t)(nloc + lrow) * 64 + c8] = v;
    else if (s == 1) *(uint4*)&kb[base + (size_t)(nloc + lrow) * 64 + c8] = v;
    else             *(uint4*)&vT[base + (size_t)lrow * 1024 + nloc + c8] = v;
  }
  // ---- fused colsum: s==2 waves reduce their 64n x 64d v-tile over n
  if (s == 2) {
#pragma unroll
    for (int ni = 0; ni < 4; ++ni) {
      float p = 0.f;
#pragma unroll
      for (int mi = 0; mi < 4; ++mi)
#pragma unroll
        for (int r = 0; r < 4; ++r) p += bf2f(f2bf(acc[mi][ni][r]));
      p += __shfl_xor(p, 16, 64);
      p += __shfl_xor(p, 32, 64);
      if ((lane >> 4) == 0)
        atomicAdd(&colsum[(b_ * 6 + h) * 64 + ni * 16 + fr], p);
    }
  }
}

// ---------------- K2a: S = (q @ k^T) * SCALE (coalesced epilogue) ----------------
__global__ __launch_bounds__(256, 3) void k_qk(const u16* __restrict__ qb,
                                               const u16* __restrict__ kb,
                                               u16* __restrict__ S) {
  __shared__ u16 SH[16384];
  u16* As = SH;
  u16* Bs = SH + 8192;
  const int t = threadIdx.x;
  const int m0 = blockIdx.x * 128, n0 = blockIdx.y * 128;
  const int bh = blockIdx.z;
  const u16* A = qb + ((size_t)bh << 16);
  const u16* Bp = kb + ((size_t)bh << 16);
  const int wave = t >> 6, lane = t & 63;
  const int wm = (wave & 1) * 64, wn = (wave >> 1) * 64;
  const int fr = lane & 15;
  const int fk = (lane >> 4) * 8;
  f32x4 acc[4][4] = {};
#pragma unroll
  for (int i = 0; i < 4; ++i) {
    int e = (i * 256 + t) * 8;
    *(uint4*)&As[e] = *(const uint4*)&A[(size_t)m0 * 64 + e];
    *(uint4*)&Bs[e] = *(const uint4*)&Bp[(size_t)n0 * 64 + e];
  }
  __syncthreads();
#pragma unroll
  for (int ks = 0; ks < 2; ++ks) {
    const int ko = ks * 32 + fk;
    short8 a[4], b[4];
#pragma unroll
    for (int mi = 0; mi < 4; ++mi) a[mi] = *(const short8*)&As[(wm + mi * 16 + fr) * 64 + ko];
#pragma unroll
    for (int ni = 0; ni < 4; ++ni) b[ni] = *(const short8*)&Bs[(wn + ni * 16 + fr) * 64 + ko];
#pragma unroll
    for (int mi = 0; mi < 4; ++mi)
#pragma unroll
      for (int ni = 0; ni < 4; ++ni) acc[mi][ni] = MFMA(a[mi], b[ni], acc[mi][ni]);
  }
  __syncthreads();                        // all waves done reading As/Bs
  u16* st = &SH[wave * 4096];
#pragma unroll
  for (int mi = 0; mi < 4; ++mi)
#pragma unroll
    for (int ni = 0; ni < 4; ++ni)
#pragma unroll
      for (int r = 0; r < 4; ++r)
        st[(mi * 16 + (lane >> 4) * 4 + r) * 64 + ni * 16 + fr] = f2bf(acc[mi][ni][r] * 0.125f);
  const size_t sb = (size_t)bh << 20;
  const int grow0 = m0 + wm, gcol0 = n0 + wn;
  const int r8 = lane >> 3, c8 = (lane & 7) * 8;
#pragma unroll
  for (int i = 0; i < 8; ++i) {
    int lrow = i * 8 + r8;
    uint4 v = *(const uint4*)&st[lrow * 64 + c8];
    *(uint4*)&S[sb + (size_t)(grow0 + lrow) * 1024 + gcol0 + c8] = v;
  }
}

// ---------------- K2b: depthwise 3x3 conv + softmax, Q = N*P - 1 (bf16), per (b,h) ----------------
__global__ __launch_bounds__(256) void k_conv_softmax(const u16* __restrict__ S,
                                                      const float* __restrict__ w_kq,
                                                      u16* __restrict__ Qb) {
  __shared__ u16 Sr[10 * 1040];
  __shared__ float red[4];
  const int t = threadIdx.x;
  const int bh = blockIdx.y;
  const int h = bh % 6;
  const int r0 = blockIdx.x * 8;
  const u16* Sp = S + ((size_t)bh << 20);
  float wv[9];
#pragma unroll
  for (int i = 0; i < 9; ++i) wv[i] = w_kq[h * 9 + i];
  if (t < 10) { Sr[t * 1040 + 7] = 0; Sr[t * 1040 + 1032] = 0; }
#pragma unroll
  for (int c = 0; c < 5; ++c) {
    int e = (c * 256 + t) * 8;
    int i = e >> 10, col = e & 1023;
    int g = r0 - 1 + i;
    uint4 val = make_uint4(0u, 0u, 0u, 0u);
    if (g >= 0 && g < 1024) val = *(const uint4*)&Sp[(size_t)g * 1024 + col];
    *(uint4*)&Sr[i * 1040 + 8 + col] = val;
  }
  __syncthreads();
  const int half = t >> 7;
  const int lane = t & 63;
  const int m0 = (t & 127) * 8;
  for (int pass = 0; pass < 4; ++pass) {
    int rr = pass * 2 + half;       // output row in block (0..7)
    float o8[8];
#pragma unroll
    for (int j = 0; j < 8; ++j) o8[j] = 0.f;
#pragma unroll
    for (int i = 0; i < 3; ++i) {
      const u16* rowp = &Sr[(rr + i) * 1040 + 8];
      float left = bf2f(rowp[m0 - 1]);
      float md[8];
      unpack8(*(const uint4*)&rowp[m0], md);
      float right = bf2f(rowp[m0 + 8]);
      float w0 = wv[i * 3 + 0], w1 = wv[i * 3 + 1], w2 = wv[i * 3 + 2];
      o8[0] += w0 * left + w1 * md[0] + w2 * md[1];
#pragma unroll
      for (int j = 1; j < 7; ++j) o8[j] += w0 * md[j - 1] + w1 * md[j] + w2 * md[j + 1];
      o8[7] += w0 * md[6] + w1 * md[7] + w2 * right;
    }
    float mx = o8[0];
#pragma unroll
    for (int j = 1; j < 8; ++j) mx = fmaxf(mx, o8[j]);
    for (int off = 32; off; off >>= 1) mx = fmaxf(mx, __shfl_xor(mx, off, 64));
    if (lane == 0) red[t >> 6] = mx;
    __syncthreads();
    float rmax = fmaxf(red[half * 2], red[half * 2 + 1]);
    __syncthreads();
    float e8[8], s = 0.f;
#pragma unroll
    for (int j = 0; j < 8; ++j) { e8[j] = __expf(o8[j] - rmax); s += e8[j]; }
    for (int off = 32; off; off >>= 1) s += __shfl_xor(s, off, 64);
    if (lane == 0) red[t >> 6] = s;
    __syncthreads();
    float rsum = red[half * 2] + red[half * 2 + 1];
    __syncthreads();
    float scale = 1024.f / rsum;
    unsigned int pk[4];
#pragma unroll
    for (int jj = 0; jj < 4; ++jj)
      pk[jj] = pk2(e8[2 * jj] * scale - 1.f, e8[2 * jj + 1] * scale - 1.f);
    int n = r0 + rr;
    *(uint4*)&Qb[((size_t)bh << 20) + (size_t)n * 1024 + m0] = make_uint4(pk[0], pk[1], pk[2], pk[3]);
  }
}

// ---------------- K5: PV opair — 2 output heads share the 6 Qm streams ----------------
// grid (32, 24): 32-row n-tile; by -> (b, head-pair). Logical Qm reads per output halved.
// (256,3): VGPR cap ~168 — fits the ~107-reg live set WITHOUT spilling (r9: cap 80 -> 131 MB scratch).
__global__ __launch_bounds__(256, 3) void k_pvmix2(const u16* __restrict__ Qm,
                                                   const u16* __restrict__ vT,
                                                   const float* __restrict__ wh,
                                                   float* __restrict__ Ug,
                                                   float* __restrict__ stats) {
  __shared__ u16 SH[13056];          // Am0(2176)|Am1(2176)|Vm0(4352)|Vm1(4352), stride 68; 26 KB
  const int t = threadIdx.x;
  const int n0 = blockIdx.x * 32;
  const int by = blockIdx.y;
  const int b_ = by / 3, op = by - b_ * 3;
  const int bo0 = b_ * 6 + op * 2;
  const int wave = t >> 6, lane = t & 63;
  const int fr = lane & 15, quad = lane >> 4;
  const int oo = wave >> 1, rb = wave & 1;      // wave's (output-head, row-block)
  const int srow = t >> 3, smg8 = (t & 7) * 8;  // staging: n-local row srow (0..31)
  float wo0[6], wo1[6];
#pragma unroll
  for (int hh = 0; hh < 6; ++hh) {
    wo0[hh] = wh[(op * 2 + 0) * 6 + hh];
    wo1[hh] = wh[(op * 2 + 1) * 6 + hh];
  }
  const size_t qbase = ((size_t)(b_ * 6)) << 20;
  const u16* vp0 = vT + ((size_t)bo0 << 16);
  const u16* vp1 = vT + ((size_t)(bo0 + 1) << 16);
  uint4 qpre[6], vpre0[2], vpre1[2];
  {
    const int m = smg8;
#pragma unroll
    for (int hh = 0; hh < 6; ++hh)
      qpre[hh] = *(const uint4*)&Qm[qbase + (((size_t)hh) << 20) + (size_t)(n0 + srow) * 1024 + m];
#pragma unroll
    for (int i = 0; i < 2; ++i) {
      vpre0[i] = *(const uint4*)&vp0[(size_t)(i * 32 + srow) * 1024 + m];
      vpre1[i] = *(const uint4*)&vp1[(size_t)(i * 32 + srow) * 1024 + m];
    }
  }
  f32x4 acc[4] = {};
  float s1o0 = 0.f, s2o0 = 0.f, s1o1 = 0.f, s2o1 = 0.f;
  for (int mc = 0; mc < 16; ++mc) {
    __syncthreads();   // prev MFMA done reading LDS
    // consume prefetched regs: dual mix + stats + stage
    {
      float mix0[8] = {0.f, 0.f, 0.f, 0.f, 0.f, 0.f, 0.f, 0.f};
      float mix1[8] = {0.f, 0.f, 0.f, 0.f, 0.f, 0.f, 0.f, 0.f};
#pragma unroll
      for (int hh = 0; hh < 6; ++hh) {
        float qf[8];
        unpack8(qpre[hh], qf);
        float w0 = wo0[hh], w1 = wo1[hh];
#pragma unroll
        for (int j = 0; j < 8; ++j) { mix0[j] += w0 * qf[j]; mix1[j] += w1 * qf[j]; }
      }
#pragma unroll
      for (int j = 0; j < 8; ++j) {
        s1o0 += mix0[j]; s2o0 += mix0[j] * mix0[j];
        s1o1 += mix1[j]; s2o1 += mix1[j] * mix1[j];
      }
      uint4 p0, p1;
      p0.x = pk2(mix0[0], mix0[1]); p0.y = pk2(mix0[2], mix0[3]);
      p0.z = pk2(mix0[4], mix0[5]); p0.w = pk2(mix0[6], mix0[7]);
      p1.x = pk2(mix1[0], mix1[1]); p1.y = pk2(mix1[2], mix1[3]);
      p1.z = pk2(mix1[4], mix1[5]); p1.w = pk2(mix1[6], mix1[7]);
      *(uint4*)&SH[srow * 68 + smg8] = p0;                 // Am0
      *(uint4*)&SH[2176 + srow * 68 + smg8] = p1;          // Am1
    }
#pragma unroll
    for (int i = 0; i < 2; ++i) {
      *(uint4*)&SH[4352 + (i * 32 + srow) * 68 + smg8] = vpre0[i];   // Vm0
      *(uint4*)&SH[8704 + (i * 32 + srow) * 68 + smg8] = vpre1[i];   // Vm1
    }
    // prefetch next chunk (overlaps barrier + MFMA)
    if (mc < 15) {
      const int m = (mc + 1) * 64 + smg8;
#pragma unroll
      for (int hh = 0; hh < 6; ++hh)
        qpre[hh] = *(const uint4*)&Qm[qbase + (((size_t)hh) << 20) + (size_t)(n0 + srow) * 1024 + m];
#pragma unroll
      for (int i = 0; i < 2; ++i) {
        vpre0[i] = *(const uint4*)&vp0[(size_t)(i * 32 + srow) * 1024 + m];
        vpre1[i] = *(const uint4*)&vp1[(size_t)(i * 32 + srow) * 1024 + m];
      }
    }
    __syncthreads();   // staging visible
    const u16* Amw = SH + oo * 2176;
    const u16* Vmw = SH + 4352 + oo * 4352;
#pragma unroll
    for (int ks = 0; ks < 2; ++ks) {
      short8 a = *(const short8*)&Amw[(rb * 16 + fr) * 68 + ks * 32 + quad * 8];
#pragma unroll
      for (int ni = 0; ni < 4; ++ni) {
        short8 b = *(const short8*)&Vmw[(ni * 16 + fr) * 68 + ks * 32 + quad * 8];
        acc[ni] = MFMA(a, b, acc[ni]);
      }
    }
  }
  __syncthreads();                   // all MFMA done before LDS reuse
  // ---- epilogue: stage both U tiles (32 n x 64 d f32 each) in LDS, stream contiguously
  float* FS = (float*)SH;            // 4096 f32 = 16 KB
#pragma unroll
  for (int ni = 0; ni < 4; ++ni)
#pragma unroll
    for (int r = 0; r < 4; ++r)
      FS[oo * 2048 + (rb * 16 + quad * 4 + r) * 64 + ni * 16 + fr] = acc[ni][r];
  __syncthreads();
  float* Up0 = Ug + ((size_t)(bo0 * 1024 + n0)) * 64;
  float* Up1 = Ug + ((size_t)((bo0 + 1) * 1024 + n0)) * 64;
#pragma unroll
  for (int j = 0; j < 2; ++j) {
    int idx = (j * 256 + t) * 4;
    *(float4*)&Up0[idx] = *(const float4*)&FS[idx];
    *(float4*)&Up1[idx] = *(const float4*)&FS[2048 + idx];
  }
  for (int off = 32; off; off >>= 1) {
    s1o0 += __shfl_xor(s1o0, off, 64);
    s2o0 += __shfl_xor(s2o0, off, 64);
    s1o1 += __shfl_xor(s1o1, off, 64);
    s2o1 += __shfl_xor(s2o1, off, 64);
  }
  if (lane == 0) {
    atomicAdd(&stats[bo0 * 2 + 0], s1o0);
    atomicAdd(&stats[bo0 * 2 + 1], s2o0);
    atomicAdd(&stats[(bo0 + 1) * 2 + 0], s1o1);
    atomicAdd(&stats[(bo0 + 1) * 2 + 1], s2o1);
  }
}

// ---------------- apply (finalize folded): o_tmp = alpha*U + beta*colsum ----------------
__global__ __launch_bounds__(256) void k_apply(const float* __restrict__ Ug,
                                               const float* __restrict__ stats,
                                               const float* __restrict__ colsum,
                                               const float* __restrict__ gn_w,
                                               const float* __restrict__ gn_b,
                                               u16* __restrict__ otmp) {
  int i = blockIdx.x * 256 + threadIdx.x;
  int e = i * 4;
  int d4 = e & 63;
  int n = (e >> 6) & 1023;
  int bo = e >> 16;
  int b = bo / 6, o = bo - b * 6;
  float s1 = stats[bo * 2], s2 = stats[bo * 2 + 1];
  const float inv = 1.f / 1048576.f;
  float mu = s1 * inv;
  float var = s2 * inv - mu * mu;
  float alpha = gn_w[o] * rsqrtf(var + 1e-5f * 1048576.f);
  float beta = gn_b[o] - alpha * mu;
  float4 cs = *(const float4*)&colsum[bo * 64 + d4];
  float4 u = *(const float4*)&Ug[e];
  uint2 w;
  w.x = pk2(alpha * u.x + beta * cs.x, alpha * u.y + beta * cs.y);
  w.y = pk2(alpha * u.z + beta * cs.z, alpha * u.w + beta * cs.w);
  *(uint2*)&otmp[((size_t)(b * 1024 + n)) * 384 + o * 64 + d4] = w;
}

// ---------------- K6: out(F32) = o_tmp @ w_proj^T + b_proj (coalesced epilogue) ----------------
__global__ __launch_bounds__(256, 3) void k_proj(const u16* __restrict__ A,
                                                 const float* __restrict__ w,
                                                 const float* __restrict__ bias,
                                                 float* __restrict__ out) {
  __shared__ u16 SH[16384];
  u16* As = SH;
  u16* Bs = SH + 8192;
  const int t = threadIdx.x;
  const int m0 = blockIdx.x * 128;
  const int n0 = blockIdx.y * 128;
  const int wave = t >> 6, lane = t & 63;
  const int wm = (wave & 1) * 64, wn = (wave >> 1) * 64;
  const int fr = lane & 15;
  const int fk = (lane >> 4) * 8;
  f32x4 acc[4][4] = {};
  for (int k0 = 0; k0 < 384; k0 += 64) {
#pragma unroll
    for (int i = 0; i < 4; ++i) {
      int e = (i * 256 + t) * 8;
      int row = e >> 6, col = e & 63;
      *(uint4*)&As[e] = *(const uint4*)&A[(size_t)(m0 + row) * 384 + k0 + col];
      const float* wp = &w[(size_t)(n0 + row) * 384 + k0 + col];
      float4 b0 = *(const float4*)wp, b1 = *(const float4*)(wp + 4);
      uint4 bv; bv.x = pk2(b0.x, b0.y); bv.y = pk2(b0.z, b0.w);
      bv.z = pk2(b1.x, b1.y); bv.w = pk2(b1.z, b1.w);
      *(uint4*)&Bs[e] = bv;
    }
    __syncthreads();
#pragma unroll
    for (int ks = 0; ks < 2; ++ks) {
      const int ko = ks * 32 + fk;
      short8 a[4], b[4];
#pragma unroll
      for (int mi = 0; mi < 4; ++mi) a[mi] = *(const short8*)&As[(wm + mi * 16 + fr) * 64 + ko];
#pragma unroll
      for (int ni = 0; ni < 4; ++ni) b[ni] = *(const short8*)&Bs[(wn + ni * 16 + fr) * 64 + ko];
#pragma unroll
      for (int mi = 0; mi < 4; ++mi)
#pragma unroll
        for (int ni = 0; ni < 4; ++ni) acc[mi][ni] = MFMA(a[mi], b[ni], acc[mi][ni]);
    }
    __syncthreads();
  }
  // ---- epilogue: two half-tiles (32x64 f32 per wave) staged in LDS, full-line float4 stores
  float* FS = (float*)SH;                 // 8192 f32
  float* fst = &FS[wave * 2048];
  float bv[4];
#pragma unroll
  for (int ni = 0; ni < 4; ++ni) bv[ni] = bias[n0 + wn + ni * 16 + fr];
#pragma unroll
  for (int half = 0; half < 2; ++half) {
#pragma unroll
    for (int mi2 = 0; mi2 < 2; ++mi2) {
      int mi = half * 2 + mi2;
#pragma unroll
      for (int ni = 0; ni < 4; ++ni)
#pragma unroll
        for (int r = 0; r < 4; ++r)
          fst[(mi2 * 16 + (lane >> 4) * 4 + r) * 64 + ni * 16 + fr] = acc[mi][ni][r] + bv[ni];
    }
#pragma unroll
    for (int g = 0; g < 4; ++g)
#pragma unroll
      for (int i2 = 0; i2 < 2; ++i2) {
        int lrow = g * 8 + (lane >> 3);
        int colf = i2 * 32 + (lane & 7) * 4;
        float4 v = *(const float4*)&fst[lrow * 64 + colf];
        *(float4*)&out[(size_t)(m0 + wm + half * 32 + lrow) * 384 + n0 + wn + colf] = v;
      }
  }
}

extern "C" void kernel_launch(void* const* d_in, const int* in_sizes, int n_in,
                              void* d_out, int out_size, void* d_ws, size_t ws_size,
                              hipStream_t stream) {
  (void)in_sizes; (void)n_in; (void)out_size; (void)ws_size;
  const float* x      = (const float*)d_in[0];
  const float* w_qkv  = (const float*)d_in[1];
  const float* w_proj = (const float*)d_in[2];
  const float* b_proj = (const float*)d_in[3];
  const float* w_kq   = (const float*)d_in[4];
  // d_in[5] b_kq: constant per map -> softmax-invariant, unused
  const float* w_head = (const float*)d_in[6];
  // d_in[7] b_head: constant per (b,o) map -> cancelled by GroupNorm, unused
  const float* gn_w   = (const float*)d_in[8];
  const float* gn_b   = (const float*)d_in[9];

  char* ws = (char*)d_ws;
  u16*   qb      = (u16*)(ws + OFF_Q);
  u16*   kb      = (u16*)(ws + OFF_K);
  u16*   vT      = (u16*)(ws + OFF_VT);
  u16*   Sb      = (u16*)(ws + OFF_S);
  float* Ug      = (float*)(ws + OFF_UG);   // aliases S (dead after conv)
  u16*   Qm      = (u16*)(ws + OFF_QM);     // per-head N*P-1 maps
  u16*   otmp    = (u16*)(ws + OFF_OT);
  float* stats   = (float*)(ws + OFF_ST);
  float* colsum  = (float*)(ws + OFF_CS);

  hipMemsetAsync(stats, 0, 896 + 12288, stream);   // stats + colsum
  k_qkv<<<dim3(64, 9), 256, 0, stream>>>(x, w_qkv, qb, kb, vT, colsum);
  k_qk<<<dim3(8, 8, 48), 256, 0, stream>>>(qb, kb, Sb);
  k_conv_softmax<<<dim3(128, 48), 256, 0, stream>>>(Sb, w_kq, Qm);
  k_pvmix2<<<dim3(32, 24), 256, 0, stream>>>(Qm, vT, w_head, Ug, stats);
  k_apply<<<dim3(3072), 256, 0, stream>>>(Ug, stats, colsum, gn_w, gn_b, otmp);
  k_proj<<<dim3(64, 3), 256, 0, stream>>>(otmp, w_proj, b_proj, (float*)d_out);
}

// Round 11
// 275.570 us; speedup vs baseline: 1.2736x; 1.2736x over previous
//
#include <hip/hip_runtime.h>

typedef unsigned short u16;
typedef __attribute__((ext_vector_type(8))) short short8;
typedef __attribute__((ext_vector_type(4))) float f32x4;

#define MFMA(a, b, c) __builtin_amdgcn_mfma_f32_16x16x32_bf16((a), (b), (c), 0, 0, 0)

__device__ inline float bf2f(u16 u) {
  union { unsigned int i; float f; } w; w.i = ((unsigned int)u) << 16; return w.f;
}
__device__ inline u16 f2bf(float x) {
  union { float f; unsigned int i; } u; u.f = x;
  unsigned int r = u.i + 0x7fffu + ((u.i >> 16) & 1u);  // RNE
  return (u16)(r >> 16);
}
__device__ inline unsigned int pk2(float a, float b) {
  return (unsigned int)f2bf(a) | ((unsigned int)f2bf(b) << 16);
}
__device__ inline void unpack8(uint4 v, float* f) {
  union { unsigned int i; float g; } c;
  c.i = v.x << 16;          f[0] = c.g;
  c.i = v.x & 0xffff0000u;  f[1] = c.g;
  c.i = v.y << 16;          f[2] = c.g;
  c.i = v.y & 0xffff0000u;  f[3] = c.g;
  c.i = v.z << 16;          f[4] = c.g;
  c.i = v.z & 0xffff0000u;  f[5] = c.g;
  c.i = v.w << 16;          f[6] = c.g;
  c.i = v.w & 0xffff0000u;  f[7] = c.g;
}

// ---------------- workspace layout (bytes) ----------------
static const size_t SZ_QKV = (size_t)48 * 1024 * 64 * 2;     // 6,291,456
static const size_t SZ_MAP = (size_t)48 * 1024 * 1024 * 2;   // 100,663,296
static const size_t OFF_Q  = 0;
static const size_t OFF_K  = OFF_Q + SZ_QKV;
static const size_t OFF_VT = OFF_K + SZ_QKV;
static const size_t OFF_S  = OFF_VT + SZ_QKV;                // S bf16; DEAD after conv -> U aliases
static const size_t OFF_UG = OFF_S;                          // U f32 [48][1024][64] (aliases S)
static const size_t OFF_QM = OFF_S + SZ_MAP;                 // Q = N*P-1 bf16 [48 bh][1024][1024]
static const size_t OFF_OT = OFF_QM + SZ_MAP;                // o_tmp [B,N,C] bf16
static const size_t OFF_ST = OFF_OT + SZ_QKV;                // stats 48*2 f32
static const size_t OFF_CS = OFF_ST + 896;                   // colsum_v 48*64 f32

// ---------------- K1: qkv = x @ w_qkv^T, scatter to q,k,vT + fused colsum ----------------
__global__ __launch_bounds__(256, 3) void k_qkv(const float* __restrict__ x,
                                                const float* __restrict__ w,
                                                u16* __restrict__ qb,
                                                u16* __restrict__ kb,
                                                u16* __restrict__ vT,
                                                float* __restrict__ colsum) {
  __shared__ u16 SH[16384];          // As | Bs ; reused as epilogue staging
  u16* As = SH;
  u16* Bs = SH + 8192;
  const int t = threadIdx.x;
  const int m0 = blockIdx.x * 128;
  const int n0 = blockIdx.y * 128;
  const int wave = t >> 6, lane = t & 63;
  const int wm = (wave & 1) * 64, wn = (wave >> 1) * 64;
  const int fr = lane & 15;
  const int fk = (lane >> 4) * 8;
  f32x4 acc[4][4] = {};
  for (int k0 = 0; k0 < 384; k0 += 64) {
#pragma unroll
    for (int i = 0; i < 4; ++i) {
      int e = (i * 256 + t) * 8;
      int row = e >> 6, col = e & 63;
      const float* xp = &x[(size_t)(m0 + row) * 384 + k0 + col];
      const float* wp = &w[(size_t)(n0 + row) * 384 + k0 + col];
      float4 a0 = *(const float4*)xp, a1 = *(const float4*)(xp + 4);
      uint4 av; av.x = pk2(a0.x, a0.y); av.y = pk2(a0.z, a0.w);
      av.z = pk2(a1.x, a1.y); av.w = pk2(a1.z, a1.w);
      *(uint4*)&As[e] = av;
      float4 b0 = *(const float4*)wp, b1 = *(const float4*)(wp + 4);
      uint4 bv; bv.x = pk2(b0.x, b0.y); bv.y = pk2(b0.z, b0.w);
      bv.z = pk2(b1.x, b1.y); bv.w = pk2(b1.z, b1.w);
      *(uint4*)&Bs[e] = bv;
    }
    __syncthreads();
#pragma unroll
    for (int ks = 0; ks < 2; ++ks) {
      const int ko = ks * 32 + fk;
      short8 a[4], b[4];
#pragma unroll
      for (int mi = 0; mi < 4; ++mi) a[mi] = *(const short8*)&As[(wm + mi * 16 + fr) * 64 + ko];
#pragma unroll
      for (int ni = 0; ni < 4; ++ni) b[ni] = *(const short8*)&Bs[(wn + ni * 16 + fr) * 64 + ko];
#pragma unroll
      for (int mi = 0; mi < 4; ++mi)
#pragma unroll
        for (int ni = 0; ni < 4; ++ni) acc[mi][ni] = MFMA(a[mi], b[ni], acc[mi][ni]);
    }
    __syncthreads();
  }
  // ---- epilogue: per-wave LDS transpose, then full-line uint4 stores
  u16* st = &SH[wave * 4096];
  const int gcb = n0 + wn;                 // 64-aligned -> single (s,h) per wave
  const int s = gcb / 384;
  const int remb = gcb - s * 384;
  const int h = remb >> 6;
#pragma unroll
  for (int mi = 0; mi < 4; ++mi)
#pragma unroll
    for (int ni = 0; ni < 4; ++ni)
#pragma unroll
      for (int r = 0; r < 4; ++r) {
        int rl = mi * 16 + (lane >> 4) * 4 + r;   // n-local 0..63
        int cl = ni * 16 + fr;                    // d-local 0..63
        u16 val = f2bf(acc[mi][ni][r]);
        if (s == 2) st[cl * 64 + rl] = val;       // transpose for vT
        else        st[rl * 64 + cl] = val;
      }
  const int gm0 = m0 + wm;                 // 64-aligned
  const int b_ = gm0 >> 10;
  const size_t base = (size_t)(b_ * 6 + h) << 16;
  const int nloc = gm0 & 1023;
  const int r8 = lane >> 3, c8 = (lane & 7) * 8;
#pragma unroll
  for (int i = 0; i < 8; ++i) {
    int lrow = i * 8 + r8;
    uint4 v = *(const uint4*)&st[lrow * 64 + c8];
    if (s == 0)      *(uint4*)&qb[base + (size_t)(nloc + lrow) * 64 + c8] = v;
    else if (s == 1) *(uint4*)&kb[base + (size_t)(nloc + lrow) * 64 + c8] = v;
    else             *(uint4*)&vT[base + (size_t)lrow * 1024 + nloc + c8] = v;
  }
  // ---- fused colsum: s==2 waves reduce their 64n x 64d v-tile over n
  if (s == 2) {
#pragma unroll
    for (int ni = 0; ni < 4; ++ni) {
      float p = 0.f;
#pragma unroll
      for (int mi = 0; mi < 4; ++mi)
#pragma unroll
        for (int r = 0; r < 4; ++r) p += bf2f(f2bf(acc[mi][ni][r]));
      p += __shfl_xor(p, 16, 64);
      p += __shfl_xor(p, 32, 64);
      if ((lane >> 4) == 0)
        atomicAdd(&colsum[(b_ * 6 + h) * 64 + ni * 16 + fr], p);
    }
  }
}

// ---------------- K2a: S = (q @ k^T) * SCALE (coalesced epilogue) ----------------
__global__ __launch_bounds__(256, 3) void k_qk(const u16* __restrict__ qb,
                                               const u16* __restrict__ kb,
                                               u16* __restrict__ S) {
  __shared__ u16 SH[16384];
  u16* As = SH;
  u16* Bs = SH + 8192;
  const int t = threadIdx.x;
  const int m0 = blockIdx.x * 128, n0 = blockIdx.y * 128;
  const int bh = blockIdx.z;
  const u16* A = qb + ((size_t)bh << 16);
  const u16* Bp = kb + ((size_t)bh << 16);
  const int wave = t >> 6, lane = t & 63;
  const int wm = (wave & 1) * 64, wn = (wave >> 1) * 64;
  const int fr = lane & 15;
  const int fk = (lane >> 4) * 8;
  f32x4 acc[4][4] = {};
#pragma unroll
  for (int i = 0; i < 4; ++i) {
    int e = (i * 256 + t) * 8;
    *(uint4*)&As[e] = *(const uint4*)&A[(size_t)m0 * 64 + e];
    *(uint4*)&Bs[e] = *(const uint4*)&Bp[(size_t)n0 * 64 + e];
  }
  __syncthreads();
#pragma unroll
  for (int ks = 0; ks < 2; ++ks) {
    const int ko = ks * 32 + fk;
    short8 a[4], b[4];
#pragma unroll
    for (int mi = 0; mi < 4; ++mi) a[mi] = *(const short8*)&As[(wm + mi * 16 + fr) * 64 + ko];
#pragma unroll
    for (int ni = 0; ni < 4; ++ni) b[ni] = *(const short8*)&Bs[(wn + ni * 16 + fr) * 64 + ko];
#pragma unroll
    for (int mi = 0; mi < 4; ++mi)
#pragma unroll
      for (int ni = 0; ni < 4; ++ni) acc[mi][ni] = MFMA(a[mi], b[ni], acc[mi][ni]);
  }
  __syncthreads();                        // all waves done reading As/Bs
  u16* st = &SH[wave * 4096];
#pragma unroll
  for (int mi = 0; mi < 4; ++mi)
#pragma unroll
    for (int ni = 0; ni < 4; ++ni)
#pragma unroll
      for (int r = 0; r < 4; ++r)
        st[(mi * 16 + (lane >> 4) * 4 + r) * 64 + ni * 16 + fr] = f2bf(acc[mi][ni][r] * 0.125f);
  const size_t sb = (size_t)bh << 20;
  const int grow0 = m0 + wm, gcol0 = n0 + wn;
  const int r8 = lane >> 3, c8 = (lane & 7) * 8;
#pragma unroll
  for (int i = 0; i < 8; ++i) {
    int lrow = i * 8 + r8;
    uint4 v = *(const uint4*)&st[lrow * 64 + c8];
    *(uint4*)&S[sb + (size_t)(grow0 + lrow) * 1024 + gcol0 + c8] = v;
  }
}

// ---------------- K2b: depthwise 3x3 conv + softmax, Q = N*P - 1 (bf16), per (b,h) ----------------
__global__ __launch_bounds__(256) void k_conv_softmax(const u16* __restrict__ S,
                                                      const float* __restrict__ w_kq,
                                                      u16* __restrict__ Qb) {
  __shared__ u16 Sr[10 * 1040];
  __shared__ float red[4];
  const int t = threadIdx.x;
  const int bh = blockIdx.y;
  const int h = bh % 6;
  const int r0 = blockIdx.x * 8;
  const u16* Sp = S + ((size_t)bh << 20);
  float wv[9];
#pragma unroll
  for (int i = 0; i < 9; ++i) wv[i] = w_kq[h * 9 + i];
  if (t < 10) { Sr[t * 1040 + 7] = 0; Sr[t * 1040 + 1032] = 0; }
#pragma unroll
  for (int c = 0; c < 5; ++c) {
    int e = (c * 256 + t) * 8;
    int i = e >> 10, col = e & 1023;
    int g = r0 - 1 + i;
    uint4 val = make_uint4(0u, 0u, 0u, 0u);
    if (g >= 0 && g < 1024) val = *(const uint4*)&Sp[(size_t)g * 1024 + col];
    *(uint4*)&Sr[i * 1040 + 8 + col] = val;
  }
  __syncthreads();
  const int half = t >> 7;
  const int lane = t & 63;
  const int m0 = (t & 127) * 8;
  for (int pass = 0; pass < 4; ++pass) {
    int rr = pass * 2 + half;       // output row in block (0..7)
    float o8[8];
#pragma unroll
    for (int j = 0; j < 8; ++j) o8[j] = 0.f;
#pragma unroll
    for (int i = 0; i < 3; ++i) {
      const u16* rowp = &Sr[(rr + i) * 1040 + 8];
      float left = bf2f(rowp[m0 - 1]);
      float md[8];
      unpack8(*(const uint4*)&rowp[m0], md);
      float right = bf2f(rowp[m0 + 8]);
      float w0 = wv[i * 3 + 0], w1 = wv[i * 3 + 1], w2 = wv[i * 3 + 2];
      o8[0] += w0 * left + w1 * md[0] + w2 * md[1];
#pragma unroll
      for (int j = 1; j < 7; ++j) o8[j] += w0 * md[j - 1] + w1 * md[j] + w2 * md[j + 1];
      o8[7] += w0 * md[6] + w1 * md[7] + w2 * right;
    }
    float mx = o8[0];
#pragma unroll
    for (int j = 1; j < 8; ++j) mx = fmaxf(mx, o8[j]);
    for (int off = 32; off; off >>= 1) mx = fmaxf(mx, __shfl_xor(mx, off, 64));
    if (lane == 0) red[t >> 6] = mx;
    __syncthreads();
    float rmax = fmaxf(red[half * 2], red[half * 2 + 1]);
    __syncthreads();
    float e8[8], s = 0.f;
#pragma unroll
    for (int j = 0; j < 8; ++j) { e8[j] = __expf(o8[j] - rmax); s += e8[j]; }
    for (int off = 32; off; off >>= 1) s += __shfl_xor(s, off, 64);
    if (lane == 0) red[t >> 6] = s;
    __syncthreads();
    float rsum = red[half * 2] + red[half * 2 + 1];
    __syncthreads();
    float scale = 1024.f / rsum;
    unsigned int pk[4];
#pragma unroll
    for (int jj = 0; jj < 4; ++jj)
      pk[jj] = pk2(e8[2 * jj] * scale - 1.f, e8[2 * jj + 1] * scale - 1.f);
    int n = r0 + rr;
    *(uint4*)&Qb[((size_t)bh << 20) + (size_t)n * 1024 + m0] = make_uint4(pk[0], pk[1], pk[2], pk[3]);
  }
}

// ---------------- K5: PV mix-on-the-fly (r8-proven loop) + XCD-pinned placement ----------------
// 1D grid 768: b = bid&7 pins each batch to one XCD (bid%8 round-robin). The 6 o-blocks of a
// (n0,b) group read IDENTICAL Qm data -> per-XCD L2 serves 5/6 of q traffic (1.5 MB/group/step).
__global__ __launch_bounds__(256) void k_pvmix(const u16* __restrict__ Qm,
                                               const u16* __restrict__ vT,
                                               const float* __restrict__ wh,
                                               float* __restrict__ Ug,
                                               float* __restrict__ stats) {
  __shared__ u16 SH[2 * 64 * 72];    // Am | Vm ; f32-reused in epilogue (16 KB < 18 KB)
  u16* Am = SH;
  u16* Vm = SH + 64 * 72;
  const int t = threadIdx.x;
  const int bid = blockIdx.x;
  const int b_ = bid & 7;                       // XCD pin
  const int sidx = bid >> 3;                    // 0..95
  const int n0 = (sidx / 6) * 64;
  const int o = sidx % 6;
  const int bo = b_ * 6 + o;
  const int wave = t >> 6, lane = t & 63;
  const int fr = lane & 15, quad = lane >> 4;
  const int srow = t >> 3, smg8 = (t & 7) * 8;   // staging: rows srow, srow+32
  float wo[6];
#pragma unroll
  for (int hh = 0; hh < 6; ++hh) wo[hh] = wh[o * 6 + hh];
  const size_t qbase = ((size_t)(b_ * 6)) << 20;
  const u16* vp = vT + ((size_t)bo << 16);
  uint4 qpre[2][6];
  uint4 vpre[2];
  {
    const int m = smg8;
#pragma unroll
    for (int i = 0; i < 2; ++i)
#pragma unroll
      for (int hh = 0; hh < 6; ++hh)
        qpre[i][hh] = *(const uint4*)&Qm[qbase + (((size_t)hh) << 20) +
                                         (size_t)(n0 + i * 32 + srow) * 1024 + m];
    vpre[0] = *(const uint4*)&vp[(size_t)srow * 1024 + m];
    vpre[1] = *(const uint4*)&vp[(size_t)(32 + srow) * 1024 + m];
  }
  f32x4 acc[4] = {};
  float s1 = 0.f, s2 = 0.f;
  for (int mc = 0; mc < 16; ++mc) {
    __syncthreads();   // prev MFMA done reading Am/Vm
    // consume prefetched regs: mix + stats + stage
#pragma unroll
    for (int i = 0; i < 2; ++i) {
      float mix[8] = {0.f, 0.f, 0.f, 0.f, 0.f, 0.f, 0.f, 0.f};
#pragma unroll
      for (int hh = 0; hh < 6; ++hh) {
        float qf[8];
        unpack8(qpre[i][hh], qf);
        float w = wo[hh];
#pragma unroll
        for (int j = 0; j < 8; ++j) mix[j] += w * qf[j];
      }
#pragma unroll
      for (int j = 0; j < 8; ++j) { s1 += mix[j]; s2 += mix[j] * mix[j]; }
      uint4 pk4;
      pk4.x = pk2(mix[0], mix[1]); pk4.y = pk2(mix[2], mix[3]);
      pk4.z = pk2(mix[4], mix[5]); pk4.w = pk2(mix[6], mix[7]);
      *(uint4*)&Am[(i * 32 + srow) * 72 + smg8] = pk4;
    }
    *(uint4*)&Vm[srow * 72 + smg8] = vpre[0];
    *(uint4*)&Vm[(32 + srow) * 72 + smg8] = vpre[1];
    // prefetch next chunk (overlaps barrier + MFMA)
    if (mc < 15) {
      const int m = (mc + 1) * 64 + smg8;
#pragma unroll
      for (int i = 0; i < 2; ++i)
#pragma unroll
        for (int hh = 0; hh < 6; ++hh)
          qpre[i][hh] = *(const uint4*)&Qm[qbase + (((size_t)hh) << 20) +
                                           (size_t)(n0 + i * 32 + srow) * 1024 + m];
      vpre[0] = *(const uint4*)&vp[(size_t)srow * 1024 + m];
      vpre[1] = *(const uint4*)&vp[(size_t)(32 + srow) * 1024 + m];
    }
    __syncthreads();   // staging visible
#pragma unroll
    for (int ks = 0; ks < 2; ++ks) {
      short8 a = *(const short8*)&Am[(wave * 16 + fr) * 72 + ks * 32 + quad * 8];
#pragma unroll
      for (int ni = 0; ni < 4; ++ni) {
        short8 b = *(const short8*)&Vm[(ni * 16 + fr) * 72 + ks * 32 + quad * 8];
        acc[ni] = MFMA(a, b, acc[ni]);
      }
    }
  }
  __syncthreads();                   // all MFMA done before LDS reuse
  // ---- epilogue: stage U tile (64 n x 64 d f32) in LDS, stream contiguously
  float* FS = (float*)SH;
#pragma unroll
  for (int ni = 0; ni < 4; ++ni)
#pragma unroll
    for (int r = 0; r < 4; ++r)
      FS[(wave * 16 + quad * 4 + r) * 64 + ni * 16 + fr] = acc[ni][r];
  __syncthreads();
  float* Up = Ug + ((size_t)(bo * 1024 + n0)) * 64;
#pragma unroll
  for (int j = 0; j < 4; ++j) {
    int oo = j * 1024 + t * 4;
    *(float4*)&Up[oo] = *(const float4*)&FS[oo];
  }
  for (int off = 32; off; off >>= 1) {
    s1 += __shfl_xor(s1, off, 64);
    s2 += __shfl_xor(s2, off, 64);
  }
  if (lane == 0) {
    atomicAdd(&stats[bo * 2 + 0], s1);
    atomicAdd(&stats[bo * 2 + 1], s2);
  }
}

// ---------------- apply (finalize folded): o_tmp = alpha*U + beta*colsum ----------------
__global__ __launch_bounds__(256) void k_apply(const float* __restrict__ Ug,
                                               const float* __restrict__ stats,
                                               const float* __restrict__ colsum,
                                               const float* __restrict__ gn_w,
                                               const float* __restrict__ gn_b,
                                               u16* __restrict__ otmp) {
  int i = blockIdx.x * 256 + threadIdx.x;
  int e = i * 4;
  int d4 = e & 63;
  int n = (e >> 6) & 1023;
  int bo = e >> 16;
  int b = bo / 6, o = bo - b * 6;
  float s1 = stats[bo * 2], s2 = stats[bo * 2 + 1];
  const float inv = 1.f / 1048576.f;
  float mu = s1 * inv;
  float var = s2 * inv - mu * mu;
  float alpha = gn_w[o] * rsqrtf(var + 1e-5f * 1048576.f);
  float beta = gn_b[o] - alpha * mu;
  float4 cs = *(const float4*)&colsum[bo * 64 + d4];
  float4 u = *(const float4*)&Ug[e];
  uint2 w;
  w.x = pk2(alpha * u.x + beta * cs.x, alpha * u.y + beta * cs.y);
  w.y = pk2(alpha * u.z + beta * cs.z, alpha * u.w + beta * cs.w);
  *(uint2*)&otmp[((size_t)(b * 1024 + n)) * 384 + o * 64 + d4] = w;
}

// ---------------- K6: out(F32) = o_tmp @ w_proj^T + b_proj (coalesced epilogue) ----------------
__global__ __launch_bounds__(256, 3) void k_proj(const u16* __restrict__ A,
                                                 const float* __restrict__ w,
                                                 const float* __restrict__ bias,
                                                 float* __restrict__ out) {
  __shared__ u16 SH[16384];
  u16* As = SH;
  u16* Bs = SH + 8192;
  const int t = threadIdx.x;
  const int m0 = blockIdx.x * 128;
  const int n0 = blockIdx.y * 128;
  const int wave = t >> 6, lane = t & 63;
  const int wm = (wave & 1) * 64, wn = (wave >> 1) * 64;
  const int fr = lane & 15;
  const int fk = (lane >> 4) * 8;
  f32x4 acc[4][4] = {};
  for (int k0 = 0; k0 < 384; k0 += 64) {
#pragma unroll
    for (int i = 0; i < 4; ++i) {
      int e = (i * 256 + t) * 8;
      int row = e >> 6, col = e & 63;
      *(uint4*)&As[e] = *(const uint4*)&A[(size_t)(m0 + row) * 384 + k0 + col];
      const float* wp = &w[(size_t)(n0 + row) * 384 + k0 + col];
      float4 b0 = *(const float4*)wp, b1 = *(const float4*)(wp + 4);
      uint4 bv; bv.x = pk2(b0.x, b0.y); bv.y = pk2(b0.z, b0.w);
      bv.z = pk2(b1.x, b1.y); bv.w = pk2(b1.z, b1.w);
      *(uint4*)&Bs[e] = bv;
    }
    __syncthreads();
#pragma unroll
    for (int ks = 0; ks < 2; ++ks) {
      const int ko = ks * 32 + fk;
      short8 a[4], b[4];
#pragma unroll
      for (int mi = 0; mi < 4; ++mi) a[mi] = *(const short8*)&As[(wm + mi * 16 + fr) * 64 + ko];
#pragma unroll
      for (int ni = 0; ni < 4; ++ni) b[ni] = *(const short8*)&Bs[(wn + ni * 16 + fr) * 64 + ko];
#pragma unroll
      for (int mi = 0; mi < 4; ++mi)
#pragma unroll
        for (int ni = 0; ni < 4; ++ni) acc[mi][ni] = MFMA(a[mi], b[ni], acc[mi][ni]);
    }
    __syncthreads();
  }
  // ---- epilogue: two half-tiles (32x64 f32 per wave) staged in LDS, full-line float4 stores
  float* FS = (float*)SH;                 // 8192 f32
  float* fst = &FS[wave * 2048];
  float bv[4];
#pragma unroll
  for (int ni = 0; ni < 4; ++ni) bv[ni] = bias[n0 + wn + ni * 16 + fr];
#pragma unroll
  for (int half = 0; half < 2; ++half) {
#pragma unroll
    for (int mi2 = 0; mi2 < 2; ++mi2) {
      int mi = half * 2 + mi2;
#pragma unroll
      for (int ni = 0; ni < 4; ++ni)
#pragma unroll
        for (int r = 0; r < 4; ++r)
          fst[(mi2 * 16 + (lane >> 4) * 4 + r) * 64 + ni * 16 + fr] = acc[mi][ni][r] + bv[ni];
    }
#pragma unroll
    for (int g = 0; g < 4; ++g)
#pragma unroll
      for (int i2 = 0; i2 < 2; ++i2) {
        int lrow = g * 8 + (lane >> 3);
        int colf = i2 * 32 + (lane & 7) * 4;
        float4 v = *(const float4*)&fst[lrow * 64 + colf];
        *(float4*)&out[(size_t)(m0 + wm + half * 32 + lrow) * 384 + n0 + wn + colf] = v;
      }
  }
}

extern "C" void kernel_launch(void* const* d_in, const int* in_sizes, int n_in,
                              void* d_out, int out_size, void* d_ws, size_t ws_size,
                              hipStream_t stream) {
  (void)in_sizes; (void)n_in; (void)out_size; (void)ws_size;
  const float* x      = (const float*)d_in[0];
  const float* w_qkv  = (const float*)d_in[1];
  const float* w_proj = (const float*)d_in[2];
  const float* b_proj = (const float*)d_in[3];
  const float* w_kq   = (const float*)d_in[4];
  // d_in[5] b_kq: constant per map -> softmax-invariant, unused
  const float* w_head = (const float*)d_in[6];
  // d_in[7] b_head: constant per (b,o) map -> cancelled by GroupNorm, unused
  const float* gn_w   = (const float*)d_in[8];
  const float* gn_b   = (const float*)d_in[9];

  char* ws = (char*)d_ws;
  u16*   qb      = (u16*)(ws + OFF_Q);
  u16*   kb      = (u16*)(ws + OFF_K);
  u16*   vT      = (u16*)(ws + OFF_VT);
  u16*   Sb      = (u16*)(ws + OFF_S);
  float* Ug      = (float*)(ws + OFF_UG);   // aliases S (dead after conv)
  u16*   Qm      = (u16*)(ws + OFF_QM);     // per-head N*P-1 maps
  u16*   otmp    = (u16*)(ws + OFF_OT);
  float* stats   = (float*)(ws + OFF_ST);
  float* colsum  = (float*)(ws + OFF_CS);

  hipMemsetAsync(stats, 0, 896 + 12288, stream);   // stats + colsum
  k_qkv<<<dim3(64, 9), 256, 0, stream>>>(x, w_qkv, qb, kb, vT, colsum);
  k_qk<<<dim3(8, 8, 48), 256, 0, stream>>>(qb, kb, Sb);
  k_conv_softmax<<<dim3(128, 48), 256, 0, stream>>>(Sb, w_kq, Qm);
  k_pvmix<<<dim3(768), 256, 0, stream>>>(Qm, vT, w_head, Ug, stats);
  k_apply<<<dim3(3072), 256, 0, stream>>>(Ug, stats, colsum, gn_w, gn_b, otmp);
  k_proj<<<dim3(64, 3), 256, 0, stream>>>(otmp, w_proj, b_proj, (float*)d_out);
}

// Round 12
// 275.158 us; speedup vs baseline: 1.2755x; 1.0015x over previous
//
#include <hip/hip_runtime.h>

typedef unsigned short u16;
typedef __attribute__((ext_vector_type(8))) short short8;
typedef __attribute__((ext_vector_type(4))) float f32x4;

#define MFMA(a, b, c) __builtin_amdgcn_mfma_f32_16x16x32_bf16((a), (b), (c), 0, 0, 0)

__device__ inline float bf2f(u16 u) {
  union { unsigned int i; float f; } w; w.i = ((unsigned int)u) << 16; return w.f;
}
__device__ inline u16 f2bf(float x) {
  union { float f; unsigned int i; } u; u.f = x;
  unsigned int r = u.i + 0x7fffu + ((u.i >> 16) & 1u);  // RNE
  return (u16)(r >> 16);
}
__device__ inline unsigned int pk2(float a, float b) {
  return (unsigned int)f2bf(a) | ((unsigned int)f2bf(b) << 16);
}
__device__ inline void unpack8(uint4 v, float* f) {
  union { unsigned int i; float g; } c;
  c.i = v.x << 16;          f[0] = c.g;
  c.i = v.x & 0xffff0000u;  f[1] = c.g;
  c.i = v.y << 16;          f[2] = c.g;
  c.i = v.y & 0xffff0000u;  f[3] = c.g;
  c.i = v.z << 16;          f[4] = c.g;
  c.i = v.z & 0xffff0000u;  f[5] = c.g;
  c.i = v.w << 16;          f[6] = c.g;
  c.i = v.w & 0xffff0000u;  f[7] = c.g;
}

// ---------------- workspace layout (bytes) ----------------
static const size_t SZ_QKV = (size_t)48 * 1024 * 64 * 2;     // 6,291,456
static const size_t SZ_MAP = (size_t)48 * 1024 * 1024 * 2;   // 100,663,296
static const size_t OFF_Q  = 0;
static const size_t OFF_K  = OFF_Q + SZ_QKV;
static const size_t OFF_VT = OFF_K + SZ_QKV;
static const size_t OFF_UG = OFF_VT + SZ_QKV;                // U f32 [48][1024][64] (S eliminated)
static const size_t OFF_QM = OFF_UG + SZ_MAP;                // Q = N*P-1 bf16 [48 bh][1024][1024]
static const size_t OFF_OT = OFF_QM + SZ_MAP;                // o_tmp [B,N,C] bf16
static const size_t OFF_ST = OFF_OT + SZ_QKV;                // stats 48*2 f32
static const size_t OFF_CS = OFF_ST + 896;                   // colsum_v 48*64 f32

// ---------------- K1: qkv = x @ w_qkv^T, scatter to q,k,vT + fused colsum ----------------
__global__ __launch_bounds__(256, 3) void k_qkv(const float* __restrict__ x,
                                                const float* __restrict__ w,
                                                u16* __restrict__ qb,
                                                u16* __restrict__ kb,
                                                u16* __restrict__ vT,
                                                float* __restrict__ colsum) {
  __shared__ u16 SH[16384];          // As | Bs ; reused as epilogue staging
  u16* As = SH;
  u16* Bs = SH + 8192;
  const int t = threadIdx.x;
  const int m0 = blockIdx.x * 128;
  const int n0 = blockIdx.y * 128;
  const int wave = t >> 6, lane = t & 63;
  const int wm = (wave & 1) * 64, wn = (wave >> 1) * 64;
  const int fr = lane & 15;
  const int fk = (lane >> 4) * 8;
  f32x4 acc[4][4] = {};
  for (int k0 = 0; k0 < 384; k0 += 64) {
#pragma unroll
    for (int i = 0; i < 4; ++i) {
      int e = (i * 256 + t) * 8;
      int row = e >> 6, col = e & 63;
      const float* xp = &x[(size_t)(m0 + row) * 384 + k0 + col];
      const float* wp = &w[(size_t)(n0 + row) * 384 + k0 + col];
      float4 a0 = *(const float4*)xp, a1 = *(const float4*)(xp + 4);
      uint4 av; av.x = pk2(a0.x, a0.y); av.y = pk2(a0.z, a0.w);
      av.z = pk2(a1.x, a1.y); av.w = pk2(a1.z, a1.w);
      *(uint4*)&As[e] = av;
      float4 b0 = *(const float4*)wp, b1 = *(const float4*)(wp + 4);
      uint4 bv; bv.x = pk2(b0.x, b0.y); bv.y = pk2(b0.z, b0.w);
      bv.z = pk2(b1.x, b1.y); bv.w = pk2(b1.z, b1.w);
      *(uint4*)&Bs[e] = bv;
    }
    __syncthreads();
#pragma unroll
    for (int ks = 0; ks < 2; ++ks) {
      const int ko = ks * 32 + fk;
      short8 a[4], b[4];
#pragma unroll
      for (int mi = 0; mi < 4; ++mi) a[mi] = *(const short8*)&As[(wm + mi * 16 + fr) * 64 + ko];
#pragma unroll
      for (int ni = 0; ni < 4; ++ni) b[ni] = *(const short8*)&Bs[(wn + ni * 16 + fr) * 64 + ko];
#pragma unroll
      for (int mi = 0; mi < 4; ++mi)
#pragma unroll
        for (int ni = 0; ni < 4; ++ni) acc[mi][ni] = MFMA(a[mi], b[ni], acc[mi][ni]);
    }
    __syncthreads();
  }
  // ---- epilogue: per-wave LDS transpose, then full-line uint4 stores
  u16* st = &SH[wave * 4096];
  const int gcb = n0 + wn;                 // 64-aligned -> single (s,h) per wave
  const int s = gcb / 384;
  const int remb = gcb - s * 384;
  const int h = remb >> 6;
#pragma unroll
  for (int mi = 0; mi < 4; ++mi)
#pragma unroll
    for (int ni = 0; ni < 4; ++ni)
#pragma unroll
      for (int r = 0; r < 4; ++r) {
        int rl = mi * 16 + (lane >> 4) * 4 + r;   // n-local 0..63
        int cl = ni * 16 + fr;                    // d-local 0..63
        u16 val = f2bf(acc[mi][ni][r]);
        if (s == 2) st[cl * 64 + rl] = val;       // transpose for vT
        else        st[rl * 64 + cl] = val;
      }
  const int gm0 = m0 + wm;                 // 64-aligned
  const int b_ = gm0 >> 10;
  const size_t base = (size_t)(b_ * 6 + h) << 16;
  const int nloc = gm0 & 1023;
  const int r8 = lane >> 3, c8 = (lane & 7) * 8;
#pragma unroll
  for (int i = 0; i < 8; ++i) {
    int lrow = i * 8 + r8;
    uint4 v = *(const uint4*)&st[lrow * 64 + c8];
    if (s == 0)      *(uint4*)&qb[base + (size_t)(nloc + lrow) * 64 + c8] = v;
    else if (s == 1) *(uint4*)&kb[base + (size_t)(nloc + lrow) * 64 + c8] = v;
    else             *(uint4*)&vT[base + (size_t)lrow * 1024 + nloc + c8] = v;
  }
  // ---- fused colsum: s==2 waves reduce their 64n x 64d v-tile over n
  if (s == 2) {
#pragma unroll
    for (int ni = 0; ni < 4; ++ni) {
      float p = 0.f;
#pragma unroll
      for (int mi = 0; mi < 4; ++mi)
#pragma unroll
        for (int r = 0; r < 4; ++r) p += bf2f(f2bf(acc[mi][ni][r]));
      p += __shfl_xor(p, 16, 64);
      p += __shfl_xor(p, 32, 64);
      if ((lane >> 4) == 0)
        atomicAdd(&colsum[(b_ * 6 + h) * 64 + ni * 16 + fr], p);
    }
  }
}

// ---------------- K2: FUSED qk + depthwise conv + softmax — S never leaves LDS ----------------
// Block = 14 output rows (16 computed incl. +-1 halo = one 16-row A-frag) of one (b,h) map.
// grid 3552: b = bid&7 (XCD pin -> K[b],q[b] 1.5 MB L2-resident); h = (bid>>3)%6; band = (bid>>3)/6.
// Phase 1: S[16][1024] built in LDS via K-chunk loop (r8-pvmix barrier/prefetch skeleton).
// Phase 2: conv+softmax (r8-conv pass loop verbatim), write Qm.
__global__ __launch_bounds__(256) void k_qkconv(const u16* __restrict__ qb,
                                                const u16* __restrict__ kb,
                                                const float* __restrict__ w_kq,
                                                u16* __restrict__ Qb) {
  __shared__ u16 Sr[16 * 1040];      // S band, halo cols at 7 / 1032
  __shared__ u16 Qs[16 * 68];        // q rows n0-1..n0+14 (OOB zero), stride 68
  __shared__ u16 Ks[64 * 68];        // current K chunk, stride 68
  __shared__ float red[4];
  const int t = threadIdx.x;
  const int bid = blockIdx.x;
  const int b_ = bid & 7;
  const int rest = bid >> 3;         // 0..443
  const int h = rest % 6;
  const int band = rest / 6;         // 0..73
  const int bh = b_ * 6 + h;
  const int n0 = band * 14;          // output rows n0..n0+13
  const int wave = t >> 6, lane = t & 63;
  const int fr = lane & 15, quad = lane >> 4;

  // ---- stage q rows (n0-1 .. n0+14 -> local 0..15), zero OOB; zero Sr halo cols
  if (t < 128) {
    int i = t >> 3, c8 = (t & 7) * 8;
    int g = n0 - 1 + i;
    uint4 val = make_uint4(0u, 0u, 0u, 0u);
    if (g >= 0 && g < 1024)
      val = *(const uint4*)&qb[((size_t)bh << 16) + (size_t)g * 64 + c8];
    *(uint4*)&Qs[i * 68 + c8] = val;
  }
  if (t < 16) { Sr[t * 1040 + 7] = 0; Sr[t * 1040 + 1032] = 0; }
  // preload K chunk 0 (64 rows x 64 d): 2 uint4/thread
  const u16* kp = kb + ((size_t)bh << 16);
  uint4 kreg0 = *(const uint4*)&kp[(size_t)(t >> 3) * 64 + (t & 7) * 8];
  uint4 kreg1 = *(const uint4*)&kp[(size_t)(32 + (t >> 3)) * 64 + (t & 7) * 8];

  // ---- phase 1: S = (q @ k^T)*SCALE into Sr, 16 chunks of 64 k-rows
  for (int c = 0; c < 16; ++c) {
    __syncthreads();                 // prev MFMA readers done; (c=0) q/halo visible
    *(uint4*)&Ks[(t >> 3) * 68 + (t & 7) * 8] = kreg0;
    *(uint4*)&Ks[((t >> 3) + 32) * 68 + (t & 7) * 8] = kreg1;
    if (c < 15) {
      const size_t ro = (size_t)(c + 1) * 64 * 64;
      kreg0 = *(const uint4*)&kp[ro + (size_t)(t >> 3) * 64 + (t & 7) * 8];
      kreg1 = *(const uint4*)&kp[ro + (size_t)(32 + (t >> 3)) * 64 + (t & 7) * 8];
    }
    __syncthreads();                 // Ks visible
    f32x4 acc = {};
#pragma unroll
    for (int ks = 0; ks < 2; ++ks) {
      short8 a = *(const short8*)&Qs[fr * 68 + ks * 32 + quad * 8];
      short8 bfr = *(const short8*)&Ks[(wave * 16 + fr) * 68 + ks * 32 + quad * 8];
      acc = MFMA(a, bfr, acc);
    }
#pragma unroll
    for (int r = 0; r < 4; ++r)
      Sr[(quad * 4 + r) * 1040 + 8 + c * 64 + wave * 16 + fr] = f2bf(acc[r] * 0.125f);
  }
  __syncthreads();                   // Sr complete

  // ---- phase 2: conv + softmax (r8 structure), 7 passes x 2 rows
  float wv[9];
#pragma unroll
  for (int i = 0; i < 9; ++i) wv[i] = w_kq[h * 9 + i];
  const int half = t >> 7;
  const int m0 = (t & 127) * 8;
  for (int pass = 0; pass < 7; ++pass) {
    int rr = pass * 2 + half;        // output row in band (0..13)
    float o8[8];
#pragma unroll
    for (int j = 0; j < 8; ++j) o8[j] = 0.f;
#pragma unroll
    for (int i = 0; i < 3; ++i) {
      const u16* rowp = &Sr[(rr + i) * 1040 + 8];
      float left = bf2f(rowp[m0 - 1]);
      float md[8];
      unpack8(*(const uint4*)&rowp[m0], md);
      float right = bf2f(rowp[m0 + 8]);
      float w0 = wv[i * 3 + 0], w1 = wv[i * 3 + 1], w2 = wv[i * 3 + 2];
      o8[0] += w0 * left + w1 * md[0] + w2 * md[1];
#pragma unroll
      for (int j = 1; j < 7; ++j) o8[j] += w0 * md[j - 1] + w1 * md[j] + w2 * md[j + 1];
      o8[7] += w0 * md[6] + w1 * md[7] + w2 * right;
    }
    float mx = o8[0];
#pragma unroll
    for (int j = 1; j < 8; ++j) mx = fmaxf(mx, o8[j]);
    for (int off = 32; off; off >>= 1) mx = fmaxf(mx, __shfl_xor(mx, off, 64));
    if (lane == 0) red[t >> 6] = mx;
    __syncthreads();
    float rmax = fmaxf(red[half * 2], red[half * 2 + 1]);
    __syncthreads();
    float e8[8], s = 0.f;
#pragma unroll
    for (int j = 0; j < 8; ++j) { e8[j] = __expf(o8[j] - rmax); s += e8[j]; }
    for (int off = 32; off; off >>= 1) s += __shfl_xor(s, off, 64);
    if (lane == 0) red[t >> 6] = s;
    __syncthreads();
    float rsum = red[half * 2] + red[half * 2 + 1];
    __syncthreads();
    float scale = 1024.f / rsum;
    int n = n0 + rr;
    if (n < 1024) {
      unsigned int pk[4];
#pragma unroll
      for (int jj = 0; jj < 4; ++jj)
        pk[jj] = pk2(e8[2 * jj] * scale - 1.f, e8[2 * jj + 1] * scale - 1.f);
      *(uint4*)&Qb[((size_t)bh << 20) + (size_t)n * 1024 + m0] = make_uint4(pk[0], pk[1], pk[2], pk[3]);
    }
  }
}

// ---------------- K5: PV mix-on-the-fly + XCD-pinned placement (r11-proven) ----------------
__global__ __launch_bounds__(256) void k_pvmix(const u16* __restrict__ Qm,
                                               const u16* __restrict__ vT,
                                               const float* __restrict__ wh,
                                               float* __restrict__ Ug,
                                               float* __restrict__ stats) {
  __shared__ u16 SH[2 * 64 * 72];    // Am | Vm ; f32-reused in epilogue
  u16* Am = SH;
  u16* Vm = SH + 64 * 72;
  const int t = threadIdx.x;
  const int bid = blockIdx.x;
  const int b_ = bid & 7;                       // XCD pin
  const int sidx = bid >> 3;                    // 0..95
  const int n0 = (sidx / 6) * 64;
  const int o = sidx % 6;
  const int bo = b_ * 6 + o;
  const int wave = t >> 6, lane = t & 63;
  const int fr = lane & 15, quad = lane >> 4;
  const int srow = t >> 3, smg8 = (t & 7) * 8;   // staging: rows srow, srow+32
  float wo[6];
#pragma unroll
  for (int hh = 0; hh < 6; ++hh) wo[hh] = wh[o * 6 + hh];
  const size_t qbase = ((size_t)(b_ * 6)) << 20;
  const u16* vp = vT + ((size_t)bo << 16);
  uint4 qpre[2][6];
  uint4 vpre[2];
  {
    const int m = smg8;
#pragma unroll
    for (int i = 0; i < 2; ++i)
#pragma unroll
      for (int hh = 0; hh < 6; ++hh)
        qpre[i][hh] = *(const uint4*)&Qm[qbase + (((size_t)hh) << 20) +
                                         (size_t)(n0 + i * 32 + srow) * 1024 + m];
    vpre[0] = *(const uint4*)&vp[(size_t)srow * 1024 + m];
    vpre[1] = *(const uint4*)&vp[(size_t)(32 + srow) * 1024 + m];
  }
  f32x4 acc[4] = {};
  float s1 = 0.f, s2 = 0.f;
  for (int mc = 0; mc < 16; ++mc) {
    __syncthreads();   // prev MFMA done reading Am/Vm
#pragma unroll
    for (int i = 0; i < 2; ++i) {
      float mix[8] = {0.f, 0.f, 0.f, 0.f, 0.f, 0.f, 0.f, 0.f};
#pragma unroll
      for (int hh = 0; hh < 6; ++hh) {
        float qf[8];
        unpack8(qpre[i][hh], qf);
        float w = wo[hh];
#pragma unroll
        for (int j = 0; j < 8; ++j) mix[j] += w * qf[j];
      }
#pragma unroll
      for (int j = 0; j < 8; ++j) { s1 += mix[j]; s2 += mix[j] * mix[j]; }
      uint4 pk4;
      pk4.x = pk2(mix[0], mix[1]); pk4.y = pk2(mix[2], mix[3]);
      pk4.z = pk2(mix[4], mix[5]); pk4.w = pk2(mix[6], mix[7]);
      *(uint4*)&Am[(i * 32 + srow) * 72 + smg8] = pk4;
    }
    *(uint4*)&Vm[srow * 72 + smg8] = vpre[0];
    *(uint4*)&Vm[(32 + srow) * 72 + smg8] = vpre[1];
    if (mc < 15) {
      const int m = (mc + 1) * 64 + smg8;
#pragma unroll
      for (int i = 0; i < 2; ++i)
#pragma unroll
        for (int hh = 0; hh < 6; ++hh)
          qpre[i][hh] = *(const uint4*)&Qm[qbase + (((size_t)hh) << 20) +
                                           (size_t)(n0 + i * 32 + srow) * 1024 + m];
      vpre[0] = *(const uint4*)&vp[(size_t)srow * 1024 + m];
      vpre[1] = *(const uint4*)&vp[(size_t)(32 + srow) * 1024 + m];
    }
    __syncthreads();   // staging visible
#pragma unroll
    for (int ks = 0; ks < 2; ++ks) {
      short8 a = *(const short8*)&Am[(wave * 16 + fr) * 72 + ks * 32 + quad * 8];
#pragma unroll
      for (int ni = 0; ni < 4; ++ni) {
        short8 b = *(const short8*)&Vm[(ni * 16 + fr) * 72 + ks * 32 + quad * 8];
        acc[ni] = MFMA(a, b, acc[ni]);
      }
    }
  }
  __syncthreads();                   // all MFMA done before LDS reuse
  float* FS = (float*)SH;
#pragma unroll
  for (int ni = 0; ni < 4; ++ni)
#pragma unroll
    for (int r = 0; r < 4; ++r)
      FS[(wave * 16 + quad * 4 + r) * 64 + ni * 16 + fr] = acc[ni][r];
  __syncthreads();
  float* Up = Ug + ((size_t)(bo * 1024 + n0)) * 64;
#pragma unroll
  for (int j = 0; j < 4; ++j) {
    int oo = j * 1024 + t * 4;
    *(float4*)&Up[oo] = *(const float4*)&FS[oo];
  }
  for (int off = 32; off; off >>= 1) {
    s1 += __shfl_xor(s1, off, 64);
    s2 += __shfl_xor(s2, off, 64);
  }
  if (lane == 0) {
    atomicAdd(&stats[bo * 2 + 0], s1);
    atomicAdd(&stats[bo * 2 + 1], s2);
  }
}

// ---------------- apply (finalize folded): o_tmp = alpha*U + beta*colsum ----------------
__global__ __launch_bounds__(256) void k_apply(const float* __restrict__ Ug,
                                               const float* __restrict__ stats,
                                               const float* __restrict__ colsum,
                                               const float* __restrict__ gn_w,
                                               const float* __restrict__ gn_b,
                                               u16* __restrict__ otmp) {
  int i = blockIdx.x * 256 + threadIdx.x;
  int e = i * 4;
  int d4 = e & 63;
  int n = (e >> 6) & 1023;
  int bo = e >> 16;
  int b = bo / 6, o = bo - b * 6;
  float s1 = stats[bo * 2], s2 = stats[bo * 2 + 1];
  const float inv = 1.f / 1048576.f;
  float mu = s1 * inv;
  float var = s2 * inv - mu * mu;
  float alpha = gn_w[o] * rsqrtf(var + 1e-5f * 1048576.f);
  float beta = gn_b[o] - alpha * mu;
  float4 cs = *(const float4*)&colsum[bo * 64 + d4];
  float4 u = *(const float4*)&Ug[e];
  uint2 w;
  w.x = pk2(alpha * u.x + beta * cs.x, alpha * u.y + beta * cs.y);
  w.y = pk2(alpha * u.z + beta * cs.z, alpha * u.w + beta * cs.w);
  *(uint2*)&otmp[((size_t)(b * 1024 + n)) * 384 + o * 64 + d4] = w;
}

// ---------------- K6: out(F32) = o_tmp @ w_proj^T + b_proj (coalesced epilogue) ----------------
__global__ __launch_bounds__(256, 3) void k_proj(const u16* __restrict__ A,
                                                 const float* __restrict__ w,
                                                 const float* __restrict__ bias,
                                                 float* __restrict__ out) {
  __shared__ u16 SH[16384];
  u16* As = SH;
  u16* Bs = SH + 8192;
  const int t = threadIdx.x;
  const int m0 = blockIdx.x * 128;
  const int n0 = blockIdx.y * 128;
  const int wave = t >> 6, lane = t & 63;
  const int wm = (wave & 1) * 64, wn = (wave >> 1) * 64;
  const int fr = lane & 15;
  const int fk = (lane >> 4) * 8;
  f32x4 acc[4][4] = {};
  for (int k0 = 0; k0 < 384; k0 += 64) {
#pragma unroll
    for (int i = 0; i < 4; ++i) {
      int e = (i * 256 + t) * 8;
      int row = e >> 6, col = e & 63;
      *(uint4*)&As[e] = *(const uint4*)&A[(size_t)(m0 + row) * 384 + k0 + col];
      const float* wp = &w[(size_t)(n0 + row) * 384 + k0 + col];
      float4 b0 = *(const float4*)wp, b1 = *(const float4*)(wp + 4);
      uint4 bv; bv.x = pk2(b0.x, b0.y); bv.y = pk2(b0.z, b0.w);
      bv.z = pk2(b1.x, b1.y); bv.w = pk2(b1.z, b1.w);
      *(uint4*)&Bs[e] = bv;
    }
    __syncthreads();
#pragma unroll
    for (int ks = 0; ks < 2; ++ks) {
      const int ko = ks * 32 + fk;
      short8 a[4], b[4];
#pragma unroll
      for (int mi = 0; mi < 4; ++mi) a[mi] = *(const short8*)&As[(wm + mi * 16 + fr) * 64 + ko];
#pragma unroll
      for (int ni = 0; ni < 4; ++ni) b[ni] = *(const short8*)&Bs[(wn + ni * 16 + fr) * 64 + ko];
#pragma unroll
      for (int mi = 0; mi < 4; ++mi)
#pragma unroll
        for (int ni = 0; ni < 4; ++ni) acc[mi][ni] = MFMA(a[mi], b[ni], acc[mi][ni]);
    }
    __syncthreads();
  }
  // ---- epilogue: two half-tiles (32x64 f32 per wave) staged in LDS, full-line float4 stores
  float* FS = (float*)SH;                 // 8192 f32
  float* fst = &FS[wave * 2048];
  float bv[4];
#pragma unroll
  for (int ni = 0; ni < 4; ++ni) bv[ni] = bias[n0 + wn + ni * 16 + fr];
#pragma unroll
  for (int half = 0; half < 2; ++half) {
#pragma unroll
    for (int mi2 = 0; mi2 < 2; ++mi2) {
      int mi = half * 2 + mi2;
#pragma unroll
      for (int ni = 0; ni < 4; ++ni)
#pragma unroll
        for (int r = 0; r < 4; ++r)
          fst[(mi2 * 16 + (lane >> 4) * 4 + r) * 64 + ni * 16 + fr] = acc[mi][ni][r] + bv[ni];
    }
#pragma unroll
    for (int g = 0; g < 4; ++g)
#pragma unroll
      for (int i2 = 0; i2 < 2; ++i2) {
        int lrow = g * 8 + (lane >> 3);
        int colf = i2 * 32 + (lane & 7) * 4;
        float4 v = *(const float4*)&fst[lrow * 64 + colf];
        *(float4*)&out[(size_t)(m0 + wm + half * 32 + lrow) * 384 + n0 + wn + colf] = v;
      }
  }
}

extern "C" void kernel_launch(void* const* d_in, const int* in_sizes, int n_in,
                              void* d_out, int out_size, void* d_ws, size_t ws_size,
                              hipStream_t stream) {
  (void)in_sizes; (void)n_in; (void)out_size; (void)ws_size;
  const float* x      = (const float*)d_in[0];
  const float* w_qkv  = (const float*)d_in[1];
  const float* w_proj = (const float*)d_in[2];
  const float* b_proj = (const float*)d_in[3];
  const float* w_kq   = (const float*)d_in[4];
  // d_in[5] b_kq: constant per map -> softmax-invariant, unused
  const float* w_head = (const float*)d_in[6];
  // d_in[7] b_head: constant per (b,o) map -> cancelled by GroupNorm, unused
  const float* gn_w   = (const float*)d_in[8];
  const float* gn_b   = (const float*)d_in[9];

  char* ws = (char*)d_ws;
  u16*   qb      = (u16*)(ws + OFF_Q);
  u16*   kb      = (u16*)(ws + OFF_K);
  u16*   vT      = (u16*)(ws + OFF_VT);
  float* Ug      = (float*)(ws + OFF_UG);
  u16*   Qm      = (u16*)(ws + OFF_QM);     // per-head N*P-1 maps
  u16*   otmp    = (u16*)(ws + OFF_OT);
  float* stats   = (float*)(ws + OFF_ST);
  float* colsum  = (float*)(ws + OFF_CS);

  hipMemsetAsync(stats, 0, 896 + 12288, stream);   // stats + colsum
  k_qkv<<<dim3(64, 9), 256, 0, stream>>>(x, w_qkv, qb, kb, vT, colsum);
  k_qkconv<<<dim3(3552), 256, 0, stream>>>(qb, kb, w_kq, Qm);
  k_pvmix<<<dim3(768), 256, 0, stream>>>(Qm, vT, w_head, Ug, stats);
  k_apply<<<dim3(3072), 256, 0, stream>>>(Ug, stats, colsum, gn_w, gn_b, otmp);
  k_proj<<<dim3(64, 3), 256, 0, stream>>>(otmp, w_proj, b_proj, (float*)d_out);
}